// Round 1
// 833.185 us; speedup vs baseline: 1.6332x; 1.6332x over previous
//
#include <hip/hip_runtime.h>

typedef __attribute__((ext_vector_type(8))) short short8;
typedef __attribute__((ext_vector_type(4))) float f32x4;
typedef __attribute__((ext_vector_type(4))) int i32x4;

#define NPIX 65536
#define KPITCH 264
#define RED_KSUM 0
#define RED_VSUM 512
#define RED_AGG 1024

__device__ __forceinline__ float b2f(unsigned short u) {
  union { unsigned int i; float f; } z; z.i = ((unsigned int)u) << 16; return z.f;
}
__device__ __forceinline__ unsigned short f2b(float f) {
  union { float f; unsigned int i; } z; z.f = f;
  unsigned int r = z.i + 0x7fffu + ((z.i >> 16) & 1u);
  return (unsigned short)(r >> 16);
}
__device__ __forceinline__ unsigned int packbf(float a, float b) {
  return (unsigned int)f2b(a) | ((unsigned int)f2b(b) << 16);
}
__device__ __forceinline__ float lo16(unsigned int u) {
  union { unsigned int i; float f; } z; z.i = u << 16; return z.f;
}
__device__ __forceinline__ float hi16(unsigned int u) {
  union { unsigned int i; float f; } z; z.i = u & 0xffff0000u; return z.f;
}
// packed f32->bf16 (RNE), 1 instr per 2 values; low half also used for scalar stores
__device__ __forceinline__ int cvtpk(float a, float b) {
  int r;
  asm("v_cvt_pk_bf16_f32 %0, %1, %2" : "=v"(r) : "v"(a), "v"(b));
  return r;
}

// Build MFMA A-fragment weights (bf16) for both convs:
// wA[conv][tap][kb][mt][lane][j] = W[o=mt*16+(lane&15)][c=kb*32+(lane>>4)*8+j][tap]
// Also zero the reduction region (ws is 0xAA-poisoned before every call).
__global__ __launch_bounds__(256) void prep_kernel(
    const float* __restrict__ W1, const float* __restrict__ W2,
    unsigned short* __restrict__ wA, float* __restrict__ red)
{
  const int i = blockIdx.x * 256 + threadIdx.x;
  if (i < 73728) {
    const float* W = (i < 36864) ? W1 : W2;
    const int e = (i < 36864) ? i : (i - 36864);
    const int j    = e & 7;
    const int lane = (e >> 3) & 63;
    const int mt   = (e >> 9) & 3;
    const int kb   = (e >> 11) & 1;
    const int tap  = e >> 12;                 // 0..8 = dy*3+dx
    const int o = mt * 16 + (lane & 15);
    const int c = kb * 32 + ((lane >> 4) << 3) + j;
    wA[i] = f2b(W[o * 576 + c * 9 + tap]);
  } else if (i < 73728 + 33792) {
    red[i - 73728] = 0.0f;
  }
}

// Pass 1 (MFMA rewrite): per-pixel Q/K/V (1x1 conv) as 16x16x32 bf16 MFMA GEMMs.
// Wave = 64 px: acc lane layout o = mt*16 + 4*(l>>4) + r, px = nt*16 + (l&15)
// (same fragment recipe as the verified conv3 kernel below).
// Q: L2-normalized per px (shfl_xor column reduce), stored bf16 NCHW.
// K: normalized, staged bf16 to LDS [64ch][KPITCH px]; V staged likewise.
// agg_kv = Kn . V^T done as MFMA with k = pixels (8 k-steps over 256 px/iter),
// accumulated in VGPRs across 4 iters; one atomic pass per block at the end.
// ksum/vsum kept as fp32 VGPR partials, butterfly-reduced over l&15.
#define PROJ(WM, BM)                                                           \
    {                                                                          \
      _Pragma("unroll")                                                        \
      for (int mt = 0; mt < 4; ++mt) {                                         \
        const f32x4 bb = *(const f32x4*)((BM) + mt * 16 + g * 4);              \
        _Pragma("unroll")                                                      \
        for (int nt = 0; nt < 4; ++nt) acc[mt][nt] = bb;                       \
      }                                                                        \
      _Pragma("unroll")                                                        \
      for (int kb = 0; kb < 2; ++kb) {                                         \
        short8 af[4];                                                          \
        _Pragma("unroll")                                                      \
        for (int mt = 0; mt < 4; ++mt) {                                       \
          const float* wp = (WM) + mt * 1024 + wrow + kb * 32;                 \
          const f32x4 w0 = *(const f32x4*)wp;                                  \
          const f32x4 w1 = *(const f32x4*)(wp + 4);                            \
          union { i32x4 i; short8 s; } uw;                                     \
          uw.i.x = cvtpk(w0.x, w0.y); uw.i.y = cvtpk(w0.z, w0.w);              \
          uw.i.z = cvtpk(w1.x, w1.y); uw.i.w = cvtpk(w1.z, w1.w);              \
          af[mt] = uw.s;                                                       \
        }                                                                      \
        _Pragma("unroll")                                                      \
        for (int mt = 0; mt < 4; ++mt)                                         \
          _Pragma("unroll")                                                    \
          for (int nt = 0; nt < 4; ++nt)                                       \
            acc[mt][nt] = __builtin_amdgcn_mfma_f32_16x16x32_bf16(             \
                af[mt], bf[nt][kb], acc[mt][nt], 0, 0, 0);                     \
      }                                                                        \
    }

__global__ __launch_bounds__(256, 2) void qkv_kernel(
    const float* __restrict__ x,
    const float* __restrict__ Wq, const float* __restrict__ bq,
    const float* __restrict__ Wk, const float* __restrict__ bk,
    const float* __restrict__ Wv, const float* __restrict__ bv,
    unsigned short* __restrict__ Qn, float* __restrict__ red)
{
  __shared__ __align__(16) unsigned short ks[64 * KPITCH];
  __shared__ __align__(16) unsigned short vs[64 * KPITCH];
  const int b = blockIdx.y;
  const int t = threadIdx.x;
  const int w = t >> 6;
  const int l = t & 63;
  const int g = l >> 4;
  const int l15 = l & 15;
  const int wrow = l15 * 64 + g * 8;     // per-lane W row-slice base (floats)
  const size_t xb = (size_t)b * 64 * NPIX;

  const f32x4 zero = {0.f, 0.f, 0.f, 0.f};
  f32x4 agg[4]  = {zero, zero, zero, zero};
  f32x4 kacc[4] = {zero, zero, zero, zero};
  f32x4 vacc[4] = {zero, zero, zero, zero};

  for (int it = 0; it < 4; ++it) {
    const int pxw = (blockIdx.x << 10) + (it << 8) + (w << 6);  // wave px base

    // ---- x B-fragments (c-contiguous per lane), shared across Q,K,V ----
    short8 bf[4][2];
#pragma unroll
    for (int nt = 0; nt < 4; ++nt) {
      const float* xp = x + xb + (size_t)(g * 8) * NPIX + pxw + nt * 16 + l15;
#pragma unroll
      for (int kb = 0; kb < 2; ++kb) {
        float f[8];
#pragma unroll
        for (int j = 0; j < 8; ++j)
          f[j] = xp[(size_t)(kb * 32 + j) * NPIX];
        union { i32x4 i; short8 s; } u;
        u.i.x = cvtpk(f[0], f[1]); u.i.y = cvtpk(f[2], f[3]);
        u.i.z = cvtpk(f[4], f[5]); u.i.w = cvtpk(f[6], f[7]);
        bf[nt][kb] = u.s;
      }
    }

    f32x4 acc[4][4];

    // ---- Q: project, L2-normalize per px, store bf16 NCHW ----
    PROJ(Wq, bq);
    {
      float rq[4];
#pragma unroll
      for (int nt = 0; nt < 4; ++nt) {
        float ss = 0.f;
#pragma unroll
        for (int mt = 0; mt < 4; ++mt)
#pragma unroll
          for (int r = 0; r < 4; ++r)
            ss = fmaf(acc[mt][nt][r], acc[mt][nt][r], ss);
        ss += __shfl_xor(ss, 16);
        ss += __shfl_xor(ss, 32);
        rq[nt] = rsqrtf(ss);
      }
      unsigned short* qp = Qn + xb + pxw + l15;
#pragma unroll
      for (int mt = 0; mt < 4; ++mt)
#pragma unroll
        for (int nt = 0; nt < 4; ++nt)
#pragma unroll
          for (int r = 0; r < 4; ++r)
            qp[(size_t)(mt * 16 + g * 4 + r) * NPIX + nt * 16] =
                (unsigned short)cvtpk(acc[mt][nt][r] * rq[nt], 0.f);
    }

    // ---- K: project, normalize, accumulate ksum, stage to LDS ----
    PROJ(Wk, bk);
    {
      float rk[4];
#pragma unroll
      for (int nt = 0; nt < 4; ++nt) {
        float ss = 0.f;
#pragma unroll
        for (int mt = 0; mt < 4; ++mt)
#pragma unroll
          for (int r = 0; r < 4; ++r)
            ss = fmaf(acc[mt][nt][r], acc[mt][nt][r], ss);
        ss += __shfl_xor(ss, 16);
        ss += __shfl_xor(ss, 32);
        rk[nt] = rsqrtf(ss);
      }
#pragma unroll
      for (int mt = 0; mt < 4; ++mt)
#pragma unroll
        for (int nt = 0; nt < 4; ++nt)
#pragma unroll
          for (int r = 0; r < 4; ++r) {
            const float kn = acc[mt][nt][r] * rk[nt];
            kacc[mt][r] += kn;
            ks[(mt * 16 + g * 4 + r) * KPITCH + (w << 6) + nt * 16 + l15] =
                (unsigned short)cvtpk(kn, 0.f);
          }
    }

    // ---- V: project, accumulate vsum, stage to LDS ----
    PROJ(Wv, bv);
    {
#pragma unroll
      for (int mt = 0; mt < 4; ++mt)
#pragma unroll
        for (int nt = 0; nt < 4; ++nt)
#pragma unroll
          for (int r = 0; r < 4; ++r) {
            const float vv = acc[mt][nt][r];
            vacc[mt][r] += vv;
            vs[(mt * 16 + g * 4 + r) * KPITCH + (w << 6) + nt * 16 + l15] =
                (unsigned short)cvtpk(vv, 0.f);
          }
    }
    __syncthreads();

    // ---- agg_kv: MFMA over k = pixels (256 px this iter, 8 k-steps) ----
    // wave w owns rows ok = 16w..16w+15 (A: m=l&15); n = ov (B: n=l&15)
#pragma unroll
    for (int s = 0; s < 8; ++s) {
      const short8 ak =
          *(const short8*)(ks + (w * 16 + l15) * KPITCH + s * 32 + g * 8);
#pragma unroll
      for (int nt = 0; nt < 4; ++nt) {
        const short8 bv8 =
            *(const short8*)(vs + (nt * 16 + l15) * KPITCH + s * 32 + g * 8);
        agg[nt] = __builtin_amdgcn_mfma_f32_16x16x32_bf16(ak, bv8, agg[nt], 0, 0, 0);
      }
    }
    __syncthreads();
  }

  // ---- reductions: ksum/vsum butterfly over l&15, then global atomics ----
#pragma unroll
  for (int mt = 0; mt < 4; ++mt)
#pragma unroll
    for (int r = 0; r < 4; ++r) {
      float kv = kacc[mt][r], vv = vacc[mt][r];
#pragma unroll
      for (int d = 1; d < 16; d <<= 1) {
        kv += __shfl_xor(kv, d);
        vv += __shfl_xor(vv, d);
      }
      if (l15 == 0) {
        atomicAdd(red + RED_KSUM + b * 64 + mt * 16 + g * 4 + r, kv);
        atomicAdd(red + RED_VSUM + b * 64 + mt * 16 + g * 4 + r, vv);
      }
    }
  float* ab = red + RED_AGG + b * 4096;
#pragma unroll
  for (int nt = 0; nt < 4; ++nt)
#pragma unroll
    for (int r = 0; r < 4; ++r)
      atomicAdd(ab + (w * 16 + g * 4 + r) * 64 + nt * 16 + l15, agg[nt][r]);
}

// Pass 2: per pixel: denom, numerator = vsum + agg^T qn, *denom, then Wr 1x1.
// Output: NHWC bf16 (c contiguous per pixel) for the MFMA conv staging.
__global__ __launch_bounds__(256) void attn_kernel(
    const unsigned short* __restrict__ Qn,
    const float* __restrict__ Wr, const float* __restrict__ br,
    const float* __restrict__ red, unsigned short* __restrict__ attn)
{
  __shared__ __align__(16) unsigned short att[256 * 72];
  const int b = blockIdx.y;
  const int t = threadIdx.x;
  const int n = blockIdx.x * 256 + t;
  const size_t base = (size_t)b * 64 * NPIX + n;
  const float* ks  = red + RED_KSUM + b * 64;
  const float* vs  = red + RED_VSUM + b * 64;
  const float* agg = red + RED_AGG + b * 4096;
  float qn[64];
  float s = 0.f;
#pragma unroll
  for (int ok = 0; ok < 64; ++ok) {
    qn[ok] = b2f(Qn[base + (size_t)ok * NPIX]);
    s = fmaf(qn[ok], ks[ok] + 1e-6f, s);
  }
  const float denom = 1.0f / (65536.0f + s);
  float wvr[64];
  for (int ov = 0; ov < 64; ov += 4) {
    float a0 = vs[ov], a1 = vs[ov + 1], a2 = vs[ov + 2], a3 = vs[ov + 3];
#pragma unroll
    for (int ok = 0; ok < 64; ++ok) {
      const float qq = qn[ok];
      a0 = fmaf(agg[ok * 64 + ov    ], qq, a0);
      a1 = fmaf(agg[ok * 64 + ov + 1], qq, a1);
      a2 = fmaf(agg[ok * 64 + ov + 2], qq, a2);
      a3 = fmaf(agg[ok * 64 + ov + 3], qq, a3);
    }
    wvr[ov] = a0 * denom; wvr[ov + 1] = a1 * denom;
    wvr[ov + 2] = a2 * denom; wvr[ov + 3] = a3 * denom;
  }
  // Wr matvec; results packed 8-at-a-time into LDS [pixel][o] (pitch 72)
  for (int oc = 0; oc < 8; ++oc) {
    float rr[8];
#pragma unroll
    for (int r8 = 0; r8 < 8; r8 += 4) {
      const int o = oc * 8 + r8;
      float a0 = br[o], a1 = br[o + 1], a2 = br[o + 2], a3 = br[o + 3];
#pragma unroll
      for (int ov = 0; ov < 64; ++ov) {
        const float wv = wvr[ov];
        a0 = fmaf(Wr[(o    ) * 64 + ov], wv, a0);
        a1 = fmaf(Wr[(o + 1) * 64 + ov], wv, a1);
        a2 = fmaf(Wr[(o + 2) * 64 + ov], wv, a2);
        a3 = fmaf(Wr[(o + 3) * 64 + ov], wv, a3);
      }
      rr[r8] = a0; rr[r8 + 1] = a1; rr[r8 + 2] = a2; rr[r8 + 3] = a3;
    }
    uint4 pv;
    pv.x = packbf(rr[0], rr[1]); pv.y = packbf(rr[2], rr[3]);
    pv.z = packbf(rr[4], rr[5]); pv.w = packbf(rr[6], rr[7]);
    *(uint4*)(att + t * 72 + oc * 8) = pv;
  }
  __syncthreads();
  // dense NHWC store: wave w owns pixels w*64..w*64+63 (1KB contiguous/instr)
  const int w = t >> 6, lane = t & 63;
  const size_t wb = ((size_t)b * NPIX + (size_t)blockIdx.x * 256 + w * 64);
  const uint4* ra = (const uint4*)att + w * 64 * 9;
#pragma unroll
  for (int k = 0; k < 8; ++k) {
    const int p = (k << 3) + (lane >> 3);
    const int ch = lane & 7;
    *(uint4*)(attn + (wb + p) * 64 + ch * 8) = ra[p * 9 + ch];
  }
}

// 3x3 SAME conv, 64->64 ch, bf16 MFMA implicit GEMM.
// Tile: 32x(x) x 8(y) out pixels/block; LDS input tile 10x34 pixels, NHWC,
// c-pitch 72 shorts (16B-aligned b128 frags, 2-way-free read banks).
// Each wave: 64 o x 64 px via 4x4 tiles of mfma_f32_16x16x32_bf16.
// EPI=0: NHWC bf16 out (LDS transpose). EPI=1: fused *x+x, NCHW fp32 out.
template <int EPI>
__global__ __launch_bounds__(256, 3) void conv3_kernel(
    const unsigned short* __restrict__ in,   // NHWC bf16
    const unsigned short* __restrict__ wA,   // A-frag weights bf16
    const float* __restrict__ bias,
    const float* __restrict__ xin,           // NCHW fp32 (EPI=1)
    unsigned short* __restrict__ outh,       // NHWC bf16 (EPI=0)
    float* __restrict__ outf)                // NCHW fp32 (EPI=1)
{
  __shared__ __align__(16) unsigned short tile[10 * 34 * 72];
  const int bz = blockIdx.z;
  const int ty0 = blockIdx.y << 3;
  const int tx0 = blockIdx.x << 5;
  const int tid = threadIdx.x;
  const size_t nb = (size_t)bz * NPIX;

  // ---- stage NHWC tile (halo=1, zero-pad SAME) ----
  for (int s = tid; s < 2720; s += 256) {
    const int g = s & 7;
    const int pix = s >> 3;          // 0..339
    const int xx = pix % 34;
    const int row = pix / 34;
    const int gx = tx0 + xx - 1;
    const int gy = ty0 + row - 1;
    uint4 v = {0u, 0u, 0u, 0u};
    if ((unsigned)gx < 256u && (unsigned)gy < 256u)
      v = *(const uint4*)(in + ((nb + (gy << 8) + gx) << 6) + (g << 3));
    *(uint4*)(tile + pix * 72 + (g << 3)) = v;
  }
  __syncthreads();

  const int w = tid >> 6, lane = tid & 63, q = lane >> 4, l = lane & 15;
  f32x4 acc[4][4];
  {
#pragma unroll
    for (int mt = 0; mt < 4; ++mt) {
      const f32x4 bb = *(const f32x4*)(bias + mt * 16 + q * 4);
#pragma unroll
      for (int nt = 0; nt < 4; ++nt) acc[mt][nt] = bb;
    }
  }
  const short8* tp = (const short8*)tile;   // 72 shorts = 9 short8 per pixel
  for (int tap = 0; tap < 9; ++tap) {
    const int dy = tap / 3, dx = tap - dy * 3;
#pragma unroll
    for (int kb = 0; kb < 2; ++kb) {
      const unsigned short* wp = wA + (tap * 2 + kb) * 2048 + lane * 8;
      short8 af[4];
#pragma unroll
      for (int mt = 0; mt < 4; ++mt) af[mt] = *(const short8*)(wp + mt * 512);
      short8 bf[4];
#pragma unroll
      for (int nt = 0; nt < 4; ++nt) {
        const int yl = (w << 1) + (nt >> 1) + dy;           // 0..9
        const int xl = ((nt & 1) << 4) + l + dx;            // 0..33
        bf[nt] = tp[(yl * 34 + xl) * 9 + (kb << 2) + q];
      }
#pragma unroll
      for (int mt = 0; mt < 4; ++mt)
#pragma unroll
        for (int nt = 0; nt < 4; ++nt)
          acc[mt][nt] = __builtin_amdgcn_mfma_f32_16x16x32_bf16(
              af[mt], bf[nt], acc[mt][nt], 0, 0, 0);
    }
  }

  if (EPI == 0) {
    // NHWC bf16 epilogue: transpose C-frag -> [pixel][o] in LDS, dense store
    __syncthreads();                          // all waves done reading tile
    unsigned int* wreg = (unsigned int*)tile + w * 2304;   // 64 px * 36 uints
#pragma unroll
    for (int mt = 0; mt < 4; ++mt)
#pragma unroll
      for (int nt = 0; nt < 4; ++nt) {
        const int p = ((nt >> 1) << 5) + ((nt & 1) << 4) + l;
        unsigned int* dst = wreg + p * 36 + (mt << 3) + (q << 1);
        dst[0] = packbf(acc[mt][nt][0], acc[mt][nt][1]);
        dst[1] = packbf(acc[mt][nt][2], acc[mt][nt][3]);
      }
    __syncthreads();
    const uint4* rreg = (const uint4*)tile + w * 576;      // 64 px * 9 uint4
#pragma unroll
    for (int k = 0; k < 8; ++k) {
      const int p = (k << 3) + (lane >> 3);
      const int ch = lane & 7;
      const int gx = tx0 + (p & 31);
      const int gy = ty0 + (w << 1) + (p >> 5);
      *(uint4*)(outh + ((nb + (gy << 8) + gx) << 6) + (ch << 3)) =
          rreg[p * 9 + ch];
    }
  } else {
    // fused epilogue: out = conv*x + x, NCHW fp32
#pragma unroll
    for (int mt = 0; mt < 4; ++mt)
#pragma unroll
      for (int nt = 0; nt < 4; ++nt) {
        const int gx = tx0 + ((nt & 1) << 4) + l;
        const int gy = ty0 + (w << 1) + (nt >> 1);
#pragma unroll
        for (int r = 0; r < 4; ++r) {
          const int o = (mt << 4) + (q << 2) + r;
          const size_t idx = (((size_t)bz * 64 + o) << 16) + (gy << 8) + gx;
          const float xo = xin[idx];
          outf[idx] = fmaf(acc[mt][nt][r], xo, xo);
        }
      }
  }
}

extern "C" void kernel_launch(void* const* d_in, const int* in_sizes, int n_in,
                              void* d_out, int out_size, void* d_ws, size_t ws_size,
                              hipStream_t stream) {
  (void)in_sizes; (void)n_in; (void)out_size; (void)ws_size;
  const float* x  = (const float*)d_in[0];
  const float* Wq = (const float*)d_in[1];
  const float* bq = (const float*)d_in[2];
  const float* Wk = (const float*)d_in[3];
  const float* bk = (const float*)d_in[4];
  const float* Wv = (const float*)d_in[5];
  const float* bv = (const float*)d_in[6];
  const float* Wr = (const float*)d_in[7];
  const float* br = (const float*)d_in[8];
  const float* W1 = (const float*)d_in[9];
  const float* b1 = (const float*)d_in[10];
  const float* W2 = (const float*)d_in[11];
  const float* b2 = (const float*)d_in[12];

  // ws layout: wA1 [0,73728B) | wA2 [73728,147456B) | red 33792 fp32 | bufA
  unsigned short* wA1 = (unsigned short*)d_ws;
  unsigned short* wA2 = wA1 + 36864;
  float* red = (float*)((char*)d_ws + 147456);
  unsigned short* bufA = (unsigned short*)((char*)d_ws + 294912); // conv1 out, NHWC bf16
  // d_out (134MB fp32) doubles as scratch: first half = attn NHWC bf16,
  // second half = Qn NCHW bf16. Both fully consumed before conv2's final
  // fp32 NCHW write (stream-serialized).
  unsigned short* bufB = (unsigned short*)d_out;
  unsigned short* bufQ = (unsigned short*)((char*)d_out + 67108864);

  prep_kernel<<<420, 256, 0, stream>>>(W1, W2, wA1, red);
  qkv_kernel<<<dim3(64, 8), 256, 0, stream>>>(x, Wq, bq, Wk, bk, Wv, bv, bufQ, red);
  attn_kernel<<<dim3(256, 8), 256, 0, stream>>>(bufQ, Wr, br, red, bufB);
  conv3_kernel<0><<<dim3(8, 32, 8), 256, 0, stream>>>(
      bufB, wA1, b1, nullptr, bufA, nullptr);
  conv3_kernel<1><<<dim3(8, 32, 8), 256, 0, stream>>>(
      bufA, wA2, b2, x, nullptr, (float*)d_out);
}

// Round 2
// 599.084 us; speedup vs baseline: 2.2714x; 1.3908x over previous
//
#include <hip/hip_runtime.h>

typedef __attribute__((ext_vector_type(8))) short short8;
typedef __attribute__((ext_vector_type(4))) float f32x4;
typedef __attribute__((ext_vector_type(4))) int i32x4;

#define NPIX 65536
#define KPITCH 264
#define RED_KSUM 0
#define RED_VSUM 512
#define RED_AGG 1024

__device__ __forceinline__ float b2f(unsigned short u) {
  union { unsigned int i; float f; } z; z.i = ((unsigned int)u) << 16; return z.f;
}
__device__ __forceinline__ unsigned short f2b(float f) {
  union { float f; unsigned int i; } z; z.f = f;
  unsigned int r = z.i + 0x7fffu + ((z.i >> 16) & 1u);
  return (unsigned short)(r >> 16);
}
__device__ __forceinline__ unsigned int packbf(float a, float b) {
  return (unsigned int)f2b(a) | ((unsigned int)f2b(b) << 16);
}
// packed f32->bf16 (RNE), 1 instr per 2 values
__device__ __forceinline__ int cvtpk(float a, float b) {
  int r;
  asm("v_cvt_pk_bf16_f32 %0, %1, %2" : "=v"(r) : "v"(a), "v"(b));
  return r;
}

// Build MFMA A-fragment weights (bf16) for both convs:
// wA[conv][tap][kb][mt][lane][j] = W[o=mt*16+(lane&15)][c=kb*32+(lane>>4)*8+j][tap]
// Also zero the reduction region (ws is 0xAA-poisoned before every call).
__global__ __launch_bounds__(256) void prep_kernel(
    const float* __restrict__ W1, const float* __restrict__ W2,
    unsigned short* __restrict__ wA, float* __restrict__ red)
{
  const int i = blockIdx.x * 256 + threadIdx.x;
  if (i < 73728) {
    const float* W = (i < 36864) ? W1 : W2;
    const int e = (i < 36864) ? i : (i - 36864);
    const int j    = e & 7;
    const int lane = (e >> 3) & 63;
    const int mt   = (e >> 9) & 3;
    const int kb   = (e >> 11) & 1;
    const int tap  = e >> 12;                 // 0..8 = dy*3+dx
    const int o = mt * 16 + (lane & 15);
    const int c = kb * 32 + ((lane >> 4) << 3) + j;
    wA[i] = f2b(W[o * 576 + c * 9 + tap]);
  } else if (i < 73728 + 33792) {
    red[i - 73728] = 0.0f;
  }
}

// Pass 1: Q/K/V via 16x16x32 bf16 MFMA. Q L2-normalized, LDS-transposed,
// stored bf16 NHWC (c contiguous per px). K/V staged bf16 to LDS;
// agg_kv = Kn.V^T via MFMA over k=pixels; ksum/vsum VGPR partials.
#define PROJ(WM, BM)                                                           \
    {                                                                          \
      _Pragma("unroll")                                                        \
      for (int mt = 0; mt < 4; ++mt) {                                         \
        const f32x4 bb = *(const f32x4*)((BM) + mt * 16 + g * 4);              \
        _Pragma("unroll")                                                      \
        for (int nt = 0; nt < 4; ++nt) acc[mt][nt] = bb;                       \
      }                                                                        \
      _Pragma("unroll")                                                        \
      for (int kb = 0; kb < 2; ++kb) {                                         \
        short8 af[4];                                                          \
        _Pragma("unroll")                                                      \
        for (int mt = 0; mt < 4; ++mt) {                                       \
          const float* wp = (WM) + mt * 1024 + wrow + kb * 32;                 \
          const f32x4 w0 = *(const f32x4*)wp;                                  \
          const f32x4 w1 = *(const f32x4*)(wp + 4);                            \
          union { i32x4 i; short8 s; } uw;                                     \
          uw.i.x = cvtpk(w0.x, w0.y); uw.i.y = cvtpk(w0.z, w0.w);              \
          uw.i.z = cvtpk(w1.x, w1.y); uw.i.w = cvtpk(w1.z, w1.w);              \
          af[mt] = uw.s;                                                       \
        }                                                                      \
        _Pragma("unroll")                                                      \
        for (int mt = 0; mt < 4; ++mt)                                         \
          _Pragma("unroll")                                                    \
          for (int nt = 0; nt < 4; ++nt)                                       \
            acc[mt][nt] = __builtin_amdgcn_mfma_f32_16x16x32_bf16(             \
                af[mt], bf[nt][kb], acc[mt][nt], 0, 0, 0);                     \
      }                                                                        \
    }

__global__ __launch_bounds__(256, 2) void qkv_kernel(
    const float* __restrict__ x,
    const float* __restrict__ Wq, const float* __restrict__ bq,
    const float* __restrict__ Wk, const float* __restrict__ bk,
    const float* __restrict__ Wv, const float* __restrict__ bv,
    unsigned short* __restrict__ Qn, float* __restrict__ red)
{
  __shared__ __align__(16) unsigned short sh[2 * 64 * KPITCH];
  unsigned short* ks = sh;
  unsigned short* vs = sh + 64 * KPITCH;
  unsigned int* shu = (unsigned int*)sh;
  const int b = blockIdx.y;
  const int t = threadIdx.x;
  const int w = t >> 6;
  const int l = t & 63;
  const int g = l >> 4;
  const int l15 = l & 15;
  const int wrow = l15 * 64 + g * 8;     // per-lane W row-slice base (floats)
  const size_t xb = (size_t)b * 64 * NPIX;

  const f32x4 zero = {0.f, 0.f, 0.f, 0.f};
  f32x4 agg[4]  = {zero, zero, zero, zero};
  f32x4 kacc[4] = {zero, zero, zero, zero};
  f32x4 vacc[4] = {zero, zero, zero, zero};

  for (int it = 0; it < 4; ++it) {
    const int pxw = (blockIdx.x << 10) + (it << 8) + (w << 6);  // wave px base

    // ---- x B-fragments (c-contiguous per lane), shared across Q,K,V ----
    short8 bf[4][2];
#pragma unroll
    for (int nt = 0; nt < 4; ++nt) {
      const float* xp = x + xb + (size_t)(g * 8) * NPIX + pxw + nt * 16 + l15;
#pragma unroll
      for (int kb = 0; kb < 2; ++kb) {
        float f[8];
#pragma unroll
        for (int j = 0; j < 8; ++j)
          f[j] = xp[(size_t)(kb * 32 + j) * NPIX];
        union { i32x4 i; short8 s; } u;
        u.i.x = cvtpk(f[0], f[1]); u.i.y = cvtpk(f[2], f[3]);
        u.i.z = cvtpk(f[4], f[5]); u.i.w = cvtpk(f[6], f[7]);
        bf[nt][kb] = u.s;
      }
    }

    f32x4 acc[4][4];

    // ---- Q: project, L2-normalize, LDS transpose, dense NHWC store ----
    PROJ(Wq, bq);
    {
      float rq[4];
#pragma unroll
      for (int nt = 0; nt < 4; ++nt) {
        float ss = 0.f;
#pragma unroll
        for (int mt = 0; mt < 4; ++mt)
#pragma unroll
          for (int r = 0; r < 4; ++r)
            ss = fmaf(acc[mt][nt][r], acc[mt][nt][r], ss);
        ss += __shfl_xor(ss, 16);
        ss += __shfl_xor(ss, 32);
        rq[nt] = rsqrtf(ss);
      }
      // wave-private transpose region (pitch 72 shorts = 36 uints per px)
      unsigned int* sw = shu + w * 2304;
#pragma unroll
      for (int mt = 0; mt < 4; ++mt)
#pragma unroll
        for (int nt = 0; nt < 4; ++nt) {
          const int px = nt * 16 + l15;
          unsigned int* dst = sw + px * 36 + mt * 8 + g * 2;
          dst[0] = (unsigned)cvtpk(acc[mt][nt][0] * rq[nt], acc[mt][nt][1] * rq[nt]);
          dst[1] = (unsigned)cvtpk(acc[mt][nt][2] * rq[nt], acc[mt][nt][3] * rq[nt]);
        }
      const uint4* rr4 = (const uint4*)(shu + w * 2304);   // 9 uint4 per px
#pragma unroll
      for (int k8 = 0; k8 < 8; ++k8) {
        const int p = (k8 << 3) + (l >> 3);
        const int ch8 = l & 7;
        *(uint4*)(Qn + ((size_t)b * NPIX + pxw + p) * 64 + ch8 * 8) =
            rr4[p * 9 + ch8];
      }
      __syncthreads();   // scratch overlaps ks/vs staging regions
    }

    // ---- K: project, normalize, accumulate ksum, stage to LDS ----
    PROJ(Wk, bk);
    {
      float rk[4];
#pragma unroll
      for (int nt = 0; nt < 4; ++nt) {
        float ss = 0.f;
#pragma unroll
        for (int mt = 0; mt < 4; ++mt)
#pragma unroll
          for (int r = 0; r < 4; ++r)
            ss = fmaf(acc[mt][nt][r], acc[mt][nt][r], ss);
        ss += __shfl_xor(ss, 16);
        ss += __shfl_xor(ss, 32);
        rk[nt] = rsqrtf(ss);
      }
#pragma unroll
      for (int mt = 0; mt < 4; ++mt)
#pragma unroll
        for (int nt = 0; nt < 4; ++nt)
#pragma unroll
          for (int r = 0; r < 4; ++r) {
            const float kn = acc[mt][nt][r] * rk[nt];
            kacc[mt][r] += kn;
            ks[(mt * 16 + g * 4 + r) * KPITCH + (w << 6) + nt * 16 + l15] =
                (unsigned short)cvtpk(kn, 0.f);
          }
    }

    // ---- V: project, accumulate vsum, stage to LDS ----
    PROJ(Wv, bv);
    {
#pragma unroll
      for (int mt = 0; mt < 4; ++mt)
#pragma unroll
        for (int nt = 0; nt < 4; ++nt)
#pragma unroll
          for (int r = 0; r < 4; ++r) {
            const float vv = acc[mt][nt][r];
            vacc[mt][r] += vv;
            vs[(mt * 16 + g * 4 + r) * KPITCH + (w << 6) + nt * 16 + l15] =
                (unsigned short)cvtpk(vv, 0.f);
          }
    }
    __syncthreads();

    // ---- agg_kv: MFMA over k = pixels (256 px this iter, 8 k-steps) ----
#pragma unroll
    for (int s = 0; s < 8; ++s) {
      const short8 ak =
          *(const short8*)(ks + (w * 16 + l15) * KPITCH + s * 32 + g * 8);
#pragma unroll
      for (int nt = 0; nt < 4; ++nt) {
        const short8 bv8 =
            *(const short8*)(vs + (nt * 16 + l15) * KPITCH + s * 32 + g * 8);
        agg[nt] = __builtin_amdgcn_mfma_f32_16x16x32_bf16(ak, bv8, agg[nt], 0, 0, 0);
      }
    }
    __syncthreads();
  }

  // ---- reductions: ksum/vsum butterfly over l&15, then global atomics ----
#pragma unroll
  for (int mt = 0; mt < 4; ++mt)
#pragma unroll
    for (int r = 0; r < 4; ++r) {
      float kv = kacc[mt][r], vv = vacc[mt][r];
#pragma unroll
      for (int d = 1; d < 16; d <<= 1) {
        kv += __shfl_xor(kv, d);
        vv += __shfl_xor(vv, d);
      }
      if (l15 == 0) {
        atomicAdd(red + RED_KSUM + b * 64 + mt * 16 + g * 4 + r, kv);
        atomicAdd(red + RED_VSUM + b * 64 + mt * 16 + g * 4 + r, vv);
      }
    }
  float* ab = red + RED_AGG + b * 4096;
#pragma unroll
  for (int nt = 0; nt < 4; ++nt)
#pragma unroll
    for (int r = 0; r < 4; ++r)
      atomicAdd(ab + (w * 16 + g * 4 + r) * 64 + nt * 16 + l15, agg[nt][r]);
}

// Prep2: per batch, C = Wr.agg^T (64x64) split into bf16 hi+residual in
// MFMA A-frag layout; u = Wr.vsum; ks2 = ksum + eps.
__global__ __launch_bounds__(256) void prep2_kernel(
    const float* __restrict__ Wr, const float* __restrict__ red,
    unsigned short* __restrict__ Cb, float* __restrict__ u,
    float* __restrict__ ks2)
{
  const int b = blockIdx.y;
  const int t = threadIdx.x;
  const int o = t & 63;
  const int kq = t >> 6;                 // 0..3
  const float* wr = Wr + o * 64;
  const float* agg = red + RED_AGG + b * 4096;
#pragma unroll
  for (int i = 0; i < 4; ++i) {
    const int k = blockIdx.x * 16 + kq * 4 + i;
    const float* ar = agg + k * 64;
    float s = 0.f;
#pragma unroll
    for (int v = 0; v < 64; ++v) s = fmaf(wr[v], ar[v], s);
    const int mt = o >> 4, kb = k >> 5;
    const int lane = (o & 15) | (((k >> 3) & 3) << 4);
    const int j = k & 7;
    const unsigned short c1 = f2b(s);
    const float r1 = s - b2f(c1);
    Cb[b * 4096 + ((kb * 4 + mt) * 64 + lane) * 8 + j] = c1;
    Cb[32768 + b * 4096 + ((kb * 4 + mt) * 64 + lane) * 8 + j] = f2b(r1);
  }
  if (blockIdx.x == 0 && t < 64) {
    const float* vsr = red + RED_VSUM + b * 64;
    float s = 0.f;
#pragma unroll
    for (int v = 0; v < 64; ++v) s = fmaf(Wr[t * 64 + v], vsr[v], s);
    u[b * 64 + t] = s;
    ks2[b * 64 + t] = red[RED_KSUM + b * 64 + t] + 1e-6f;
  }
}

// Pass 2 (MFMA): attn[o,n] = denom[n]*(u[o] + C[o,:].qn[:,n]) + br[o].
// C = C1 + C2 (bf16 split) -> fp32-accurate. denom from per-lane partial
// dot with ks2 + shfl_xor reduce. Output NHWC bf16 via wave-private LDS
// transpose (no barriers needed).
__global__ __launch_bounds__(256, 2) void attn_kernel(
    const unsigned short* __restrict__ Qn,   // NHWC bf16
    const unsigned short* __restrict__ Cb,   // C1||C2 A-frags
    const float* __restrict__ u,
    const float* __restrict__ ks2,
    const float* __restrict__ br,
    unsigned short* __restrict__ attn)       // NHWC bf16
{
  __shared__ __align__(16) unsigned short att[256 * 72];
  const int b = blockIdx.y;
  const int t = threadIdx.x;
  const int w = t >> 6, l = t & 63, g = l >> 4, l15 = l & 15;

  short8 af[2][2][4];  // [lvl][kb][mt]
#pragma unroll
  for (int lvl = 0; lvl < 2; ++lvl)
#pragma unroll
    for (int kb = 0; kb < 2; ++kb)
#pragma unroll
      for (int mt = 0; mt < 4; ++mt)
        af[lvl][kb][mt] = *(const short8*)(
            Cb + lvl * 32768 + b * 4096 + ((kb * 4 + mt) * 64 + l) * 8);
  f32x4 uu[4], brf[4];
#pragma unroll
  for (int mt = 0; mt < 4; ++mt) {
    uu[mt]  = *(const f32x4*)(u + b * 64 + mt * 16 + g * 4);
    brf[mt] = *(const f32x4*)(br + mt * 16 + g * 4);
  }
  float ksl[16];
#pragma unroll
  for (int kb = 0; kb < 2; ++kb)
#pragma unroll
    for (int j = 0; j < 8; ++j)
      ksl[kb * 8 + j] = ks2[b * 64 + kb * 32 + g * 8 + j];

  for (int it = 0; it < 4; ++it) {
    const int pxw = (blockIdx.x << 10) + (it << 8) + (w << 6);
    short8 qf[4][2];
    float denom[4];
#pragma unroll
    for (int nt = 0; nt < 4; ++nt) {
      const unsigned short* qp =
          Qn + ((size_t)b * NPIX + pxw + nt * 16 + l15) * 64 + g * 8;
      qf[nt][0] = *(const short8*)qp;
      qf[nt][1] = *(const short8*)(qp + 32);
      float ss = 0.f;
#pragma unroll
      for (int kb = 0; kb < 2; ++kb)
#pragma unroll
        for (int j = 0; j < 8; ++j)
          ss = fmaf(b2f((unsigned short)qf[nt][kb][j]), ksl[kb * 8 + j], ss);
      ss += __shfl_xor(ss, 16);
      ss += __shfl_xor(ss, 32);
      denom[nt] = 1.0f / (65536.0f + ss);
    }
    f32x4 acc[4][4];
#pragma unroll
    for (int mt = 0; mt < 4; ++mt)
#pragma unroll
      for (int nt = 0; nt < 4; ++nt) acc[mt][nt] = uu[mt];
#pragma unroll
    for (int kb = 0; kb < 2; ++kb)
#pragma unroll
      for (int mt = 0; mt < 4; ++mt)
#pragma unroll
        for (int nt = 0; nt < 4; ++nt) {
          acc[mt][nt] = __builtin_amdgcn_mfma_f32_16x16x32_bf16(
              af[0][kb][mt], qf[nt][kb], acc[mt][nt], 0, 0, 0);
          acc[mt][nt] = __builtin_amdgcn_mfma_f32_16x16x32_bf16(
              af[1][kb][mt], qf[nt][kb], acc[mt][nt], 0, 0, 0);
        }
    // epilogue: val = acc*denom + br; wave-private LDS transpose, dense store
    unsigned int* sw = (unsigned int*)att + w * 2304;
#pragma unroll
    for (int mt = 0; mt < 4; ++mt)
#pragma unroll
      for (int nt = 0; nt < 4; ++nt) {
        const int px = nt * 16 + l15;
        unsigned int* dst = sw + px * 36 + mt * 8 + g * 2;
        dst[0] = (unsigned)cvtpk(fmaf(acc[mt][nt][0], denom[nt], brf[mt][0]),
                                 fmaf(acc[mt][nt][1], denom[nt], brf[mt][1]));
        dst[1] = (unsigned)cvtpk(fmaf(acc[mt][nt][2], denom[nt], brf[mt][2]),
                                 fmaf(acc[mt][nt][3], denom[nt], brf[mt][3]));
      }
    const uint4* rr4 = (const uint4*)att + w * 576;
#pragma unroll
    for (int k8 = 0; k8 < 8; ++k8) {
      const int p = (k8 << 3) + (l >> 3);
      const int ch8 = l & 7;
      *(uint4*)(attn + ((size_t)b * NPIX + pxw + p) * 64 + ch8 * 8) =
          rr4[p * 9 + ch8];
    }
  }
}

// 3x3 SAME conv, 64->64 ch, bf16 MFMA implicit GEMM.
template <int EPI>
__global__ __launch_bounds__(256, 3) void conv3_kernel(
    const unsigned short* __restrict__ in,   // NHWC bf16
    const unsigned short* __restrict__ wA,   // A-frag weights bf16
    const float* __restrict__ bias,
    const float* __restrict__ xin,           // NCHW fp32 (EPI=1)
    unsigned short* __restrict__ outh,       // NHWC bf16 (EPI=0)
    float* __restrict__ outf)                // NCHW fp32 (EPI=1)
{
  __shared__ __align__(16) unsigned short tile[10 * 34 * 72];
  const int bz = blockIdx.z;
  const int ty0 = blockIdx.y << 3;
  const int tx0 = blockIdx.x << 5;
  const int tid = threadIdx.x;
  const size_t nb = (size_t)bz * NPIX;

  // ---- stage NHWC tile (halo=1, zero-pad SAME) ----
  for (int s = tid; s < 2720; s += 256) {
    const int g = s & 7;
    const int pix = s >> 3;          // 0..339
    const int xx = pix % 34;
    const int row = pix / 34;
    const int gx = tx0 + xx - 1;
    const int gy = ty0 + row - 1;
    uint4 v = {0u, 0u, 0u, 0u};
    if ((unsigned)gx < 256u && (unsigned)gy < 256u)
      v = *(const uint4*)(in + ((nb + (gy << 8) + gx) << 6) + (g << 3));
    *(uint4*)(tile + pix * 72 + (g << 3)) = v;
  }
  __syncthreads();

  const int w = tid >> 6, lane = tid & 63, q = lane >> 4, l = lane & 15;
  f32x4 acc[4][4];
  {
#pragma unroll
    for (int mt = 0; mt < 4; ++mt) {
      const f32x4 bb = *(const f32x4*)(bias + mt * 16 + q * 4);
#pragma unroll
      for (int nt = 0; nt < 4; ++nt) acc[mt][nt] = bb;
    }
  }
  const short8* tp = (const short8*)tile;   // 72 shorts = 9 short8 per pixel
  for (int tap = 0; tap < 9; ++tap) {
    const int dy = tap / 3, dx = tap - dy * 3;
#pragma unroll
    for (int kb = 0; kb < 2; ++kb) {
      const unsigned short* wp = wA + (tap * 2 + kb) * 2048 + lane * 8;
      short8 af[4];
#pragma unroll
      for (int mt = 0; mt < 4; ++mt) af[mt] = *(const short8*)(wp + mt * 512);
      short8 bf[4];
#pragma unroll
      for (int nt = 0; nt < 4; ++nt) {
        const int yl = (w << 1) + (nt >> 1) + dy;           // 0..9
        const int xl = ((nt & 1) << 4) + l + dx;            // 0..33
        bf[nt] = tp[(yl * 34 + xl) * 9 + (kb << 2) + q];
      }
#pragma unroll
      for (int mt = 0; mt < 4; ++mt)
#pragma unroll
        for (int nt = 0; nt < 4; ++nt)
          acc[mt][nt] = __builtin_amdgcn_mfma_f32_16x16x32_bf16(
              af[mt], bf[nt], acc[mt][nt], 0, 0, 0);
    }
  }

  if (EPI == 0) {
    // NHWC bf16 epilogue: transpose C-frag -> [pixel][o] in LDS, dense store
    __syncthreads();                          // all waves done reading tile
    unsigned int* wreg = (unsigned int*)tile + w * 2304;   // 64 px * 36 uints
#pragma unroll
    for (int mt = 0; mt < 4; ++mt)
#pragma unroll
      for (int nt = 0; nt < 4; ++nt) {
        const int p = ((nt >> 1) << 5) + ((nt & 1) << 4) + l;
        unsigned int* dst = wreg + p * 36 + (mt << 3) + (q << 1);
        dst[0] = packbf(acc[mt][nt][0], acc[mt][nt][1]);
        dst[1] = packbf(acc[mt][nt][2], acc[mt][nt][3]);
      }
    __syncthreads();
    const uint4* rreg = (const uint4*)tile + w * 576;      // 64 px * 9 uint4
#pragma unroll
    for (int k = 0; k < 8; ++k) {
      const int p = (k << 3) + (lane >> 3);
      const int ch = lane & 7;
      const int gx = tx0 + (p & 31);
      const int gy = ty0 + (w << 1) + (p >> 5);
      *(uint4*)(outh + ((nb + (gy << 8) + gx) << 6) + (ch << 3)) =
          rreg[p * 9 + ch];
    }
  } else {
    // fused epilogue: out = conv*x + x, NCHW fp32
#pragma unroll
    for (int mt = 0; mt < 4; ++mt)
#pragma unroll
      for (int nt = 0; nt < 4; ++nt) {
        const int gx = tx0 + ((nt & 1) << 4) + l;
        const int gy = ty0 + (w << 1) + (nt >> 1);
#pragma unroll
        for (int r = 0; r < 4; ++r) {
          const int o = (mt << 4) + (q << 2) + r;
          const size_t idx = (((size_t)bz * 64 + o) << 16) + (gy << 8) + gx;
          const float xo = xin[idx];
          outf[idx] = fmaf(acc[mt][nt][r], xo, xo);
        }
      }
  }
}

extern "C" void kernel_launch(void* const* d_in, const int* in_sizes, int n_in,
                              void* d_out, int out_size, void* d_ws, size_t ws_size,
                              hipStream_t stream) {
  (void)in_sizes; (void)n_in; (void)out_size; (void)ws_size;
  const float* x  = (const float*)d_in[0];
  const float* Wq = (const float*)d_in[1];
  const float* bq = (const float*)d_in[2];
  const float* Wk = (const float*)d_in[3];
  const float* bk = (const float*)d_in[4];
  const float* Wv = (const float*)d_in[5];
  const float* bv = (const float*)d_in[6];
  const float* Wr = (const float*)d_in[7];
  const float* br = (const float*)d_in[8];
  const float* W1 = (const float*)d_in[9];
  const float* b1 = (const float*)d_in[10];
  const float* W2 = (const float*)d_in[11];
  const float* b2 = (const float*)d_in[12];

  // ws layout: wA1 [0,73728B) | wA2 [73728,147456B) | red 33792 fp32 | bufA.
  // Cb/u/ks2 alias bufA's first 136KB: written by prep2, read by attn,
  // overwritten only later by conv3<0> (stream-serialized).
  unsigned short* wA1 = (unsigned short*)d_ws;
  unsigned short* wA2 = wA1 + 36864;
  float* red = (float*)((char*)d_ws + 147456);
  unsigned short* bufA = (unsigned short*)((char*)d_ws + 294912); // conv1 out NHWC bf16
  unsigned short* Cb = (unsigned short*)((char*)d_ws + 294912);
  float* u_  = (float*)((char*)d_ws + 294912 + 131072);
  float* ks2 = (float*)((char*)d_ws + 294912 + 133120);
  // d_out scratch: first half = attn NHWC bf16, second half = Qn NHWC bf16.
  unsigned short* bufB = (unsigned short*)d_out;
  unsigned short* bufQ = (unsigned short*)((char*)d_out + 67108864);

  prep_kernel<<<420, 256, 0, stream>>>(W1, W2, wA1, red);
  qkv_kernel<<<dim3(64, 8), 256, 0, stream>>>(x, Wq, bq, Wk, bk, Wv, bv, bufQ, red);
  prep2_kernel<<<dim3(4, 8), 256, 0, stream>>>(Wr, red, Cb, u_, ks2);
  attn_kernel<<<dim3(64, 8), 256, 0, stream>>>(bufQ, Cb, u_, ks2, br, bufB);
  conv3_kernel<0><<<dim3(8, 32, 8), 256, 0, stream>>>(
      bufB, wA1, b1, nullptr, bufA, nullptr);
  conv3_kernel<1><<<dim3(8, 32, 8), 256, 0, stream>>>(
      bufA, wA2, b2, x, nullptr, (float*)d_out);
}